// Round 5
// baseline (419.659 us; speedup 1.0000x reference)
//
#include <hip/hip_runtime.h>

#define DIM 128
#define NCLS 40
#define NBIN 256
#define BINSH 9

typedef unsigned short ushort_t;
typedef __attribute__((ext_vector_type(8))) short bf16x8;
typedef __attribute__((ext_vector_type(4))) float f32x4;
typedef __attribute__((ext_vector_type(4))) unsigned uint4a;   // 16-B aligned

__device__ __forceinline__ ushort_t f2b(float f) {
    union { float f; unsigned u; } v; v.f = f;
    unsigned r = v.u + 0x7FFFu + ((v.u >> 16) & 1u);   // round-to-nearest-even
    return (ushort_t)(r >> 16);
}

__device__ __forceinline__ float b2f(ushort_t b) {
    union { unsigned u; float f; } v; v.u = ((unsigned)b) << 16;
    return v.f;
}

// accumulate 4 fp8(e4m3) values packed in w into a float4
__device__ __forceinline__ void acc_fp8x4(float4& a, int w) {
    a.x += __builtin_amdgcn_cvt_f32_fp8(w, 0);
    a.y += __builtin_amdgcn_cvt_f32_fp8(w, 1);
    a.z += __builtin_amdgcn_cvt_f32_fp8(w, 2);
    a.w += __builtin_amdgcn_cvt_f32_fp8(w, 3);
}

// add the two bf16 halves of u into a (low) and b (high); bit-identical to b2f+add
__device__ __forceinline__ void acc_pair(float& a, float& b, unsigned u) {
    union { unsigned x; float f; } lo, hi;
    lo.x = u << 16;
    hi.x = u & 0xFFFF0000u;
    a += lo.f;
    b += hi.f;
}

// ------- fused prep: cast + packw + packw2 + binCnt-zero + deg-zero ---------
__global__ __launch_bounds__(256) void prep_kernel(
    const float* __restrict__ x, ushort_t* __restrict__ xbf, unsigned* __restrict__ xq,
    const float* __restrict__ W1r, const float* __restrict__ W1l, ushort_t* __restrict__ Wp,
    const float* __restrict__ W2l, ushort_t* __restrict__ Wp2,
    int* __restrict__ binCnt, int* __restrict__ deg, int n4, int cb, int n)
{
    const int b = blockIdx.x;
    if (b < cb) {
        int i = b * 256 + threadIdx.x;
        if (i >= n4) return;
        f32x4 v = __builtin_nontemporal_load(((const f32x4*)x) + i);
        ushort4 o;
        o.x = f2b(v.x); o.y = f2b(v.y); o.z = f2b(v.z); o.w = f2b(v.w);
        ((ushort4*)xbf)[i] = o;
        int p = __builtin_amdgcn_cvt_pk_fp8_f32(v.x, v.y, 0, false);
        p = __builtin_amdgcn_cvt_pk_fp8_f32(v.z, v.w, p, true);
        xq[i] = (unsigned)p;
    } else if (b < cb + 128) {
        int o = (b - cb) * 256 + threadIdx.x;   // 0..32767
        int j    = o & 7;
        int lane = (o >> 3) & 63;
        int t    = (o >> 9) & 7;
        int kc   = o >> 12;
        int k = kc * 32 + (lane >> 4) * 8 + j;
        int nn = t * 16 + (lane & 15);
        float v = (k < DIM) ? W1r[k * DIM + nn] : W1l[(k - DIM) * DIM + nn];
        Wp[o] = f2b(v);
    } else if (b < cb + 152) {
        int o = (b - cb - 128) * 256 + threadIdx.x;   // 0..6143
        int j    = o & 7;
        int lane = (o >> 3) & 63;
        int rem  = o >> 9;
        int t    = rem % 3;
        int kc   = rem / 3;
        int k  = kc * 32 + (lane >> 4) * 8 + j;
        int nn = t * 16 + (lane & 15);
        Wp2[o] = (nn < NCLS) ? f2b(W2l[k * NCLS + nn]) : (ushort_t)0;
    } else if (b == cb + 152) {
        binCnt[threadIdx.x] = 0;
    } else {
        int o = (b - cb - 153) * 256 + threadIdx.x;
        if (o < n) deg[o] = 0;
    }
}

// ---------------- CSR build: deg-count -> rowptr scan -> direct scatter -----

// per-bin edge counts (bin = dst >> 9) + per-node degree via global atomics
__global__ __launch_bounds__(256) void degcount_kernel(const int* __restrict__ dst,
                                                       int* __restrict__ deg,
                                                       int* __restrict__ binCnt, int E) {
    __shared__ int hist[NBIN];
    hist[threadIdx.x] = 0;
    __syncthreads();
    const int tid = blockIdx.x * 256 + threadIdx.x;
    const int stride = gridDim.x * 256;
    for (int e = tid; e < E; e += stride) {
        int d = __builtin_nontemporal_load(dst + e);
        atomicAdd(&hist[d >> BINSH], 1);
        atomicAdd(&deg[d], 1);
    }
    __syncthreads();
    if (hist[threadIdx.x]) atomicAdd(&binCnt[threadIdx.x], hist[threadIdx.x]);
}

// block b: redundant local scan of binCnt (256 ints, L2-hot) -> bin base;
// LDS scan of its 512 degs -> row_ptr + ctr (scatter cursors). No binscan
// launch, no grid sync.
__global__ __launch_bounds__(256) void rowptr_kernel(const int* __restrict__ binCnt,
                                                     const int* __restrict__ deg,
                                                     int* __restrict__ row_ptr,
                                                     int* __restrict__ ctr, int n) {
    __shared__ int bs[NBIN];
    __shared__ int sc[512];
    const int b = blockIdx.x;
    const int t = threadIdx.x;
    bs[t] = binCnt[t];
    __syncthreads();
    for (int off = 1; off < NBIN; off <<= 1) {     // inclusive scan over bins
        int v = (t >= off) ? bs[t - off] : 0;
        __syncthreads();
        bs[t] += v;
        __syncthreads();
    }
    const int base = (b == 0) ? 0 : bs[b - 1];     // exclusive bin base (uniform)
    const int nlo = b << BINSH;
    const int n0 = nlo + t;
    const int n1 = nlo + 256 + t;
    const int d0 = (n0 < n) ? deg[n0] : 0;
    const int d1 = (n1 < n) ? deg[n1] : 0;
    sc[t] = d0;
    sc[t + 256] = d1;
    __syncthreads();
    for (int off = 1; off < 512; off <<= 1) {      // inclusive scan over 512 degs
        int v0 = (t >= off) ? sc[t - off] : 0;
        int v1 = sc[t + 256 - off];
        __syncthreads();
        sc[t] += v0;
        sc[t + 256] += v1;
        __syncthreads();
    }
    if (n0 < n) { int v = base + sc[t] - d0;       row_ptr[n0] = v; ctr[n0] = v; }
    if (n1 < n) { int v = base + sc[t + 256] - d1; row_ptr[n1] = v; ctr[n1] = v; }
    if (b == (int)gridDim.x - 1 && t == 255) row_ptr[n] = base + sc[511];
}

// direct scatter: eidx[ctr[dst]++] = src (order within a row is arbitrary;
// fp32 accumulation order only -> inside error budget)
__global__ __launch_bounds__(256) void scatter_kernel(const int* __restrict__ src,
                                                      const int* __restrict__ dst,
                                                      int* __restrict__ ctr,
                                                      int* __restrict__ eidx, int E) {
    const int tid = blockIdx.x * 256 + threadIdx.x;
    const int stride = gridDim.x * 256;
    for (int e = tid; e < E; e += stride) {
        int d = __builtin_nontemporal_load(dst + e);
        int s = __builtin_nontemporal_load(src + e);
        int slot = atomicAdd(&ctr[d], 1);
        eidx[slot] = s;
    }
}

// ---------------- compute (R3-proven forms) ----------------

// mxbf[node] = mean over CSR neighbors of xq[src] (fp8 in, fp32 accum, bf16 out)
__global__ __launch_bounds__(256) void gather128_kernel(
    const unsigned* __restrict__ xq, const int* __restrict__ row_ptr,
    const int* __restrict__ eidx, ushort_t* __restrict__ Bbf, int n)
{
    int t = blockIdx.x * 256 + threadIdx.x;
    int node = t >> 5;
    if (node >= n) return;
    int q = t & 31;
    int j  = row_ptr[node];
    int je = row_ptr[node + 1];
    const float id = 1.0f / fmaxf((float)(je - j), 1.0f);
    float4 acc = make_float4(0.f, 0.f, 0.f, 0.f);
    for (; j + 3 < je; j += 4) {
        int s0 = eidx[j], s1 = eidx[j + 1], s2 = eidx[j + 2], s3 = eidx[j + 3];
        int w0 = (int)xq[(size_t)s0 * 32 + q];
        int w1 = (int)xq[(size_t)s1 * 32 + q];
        int w2 = (int)xq[(size_t)s2 * 32 + q];
        int w3 = (int)xq[(size_t)s3 * 32 + q];
        acc_fp8x4(acc, w0); acc_fp8x4(acc, w1);
        acc_fp8x4(acc, w2); acc_fp8x4(acc, w3);
    }
    for (; j < je; ++j) {
        int s0 = eidx[j];
        acc_fp8x4(acc, (int)xq[(size_t)s0 * 32 + q]);
    }
    ushort4 o;
    o.x = f2b(acc.x * id); o.y = f2b(acc.y * id);
    o.z = f2b(acc.z * id); o.w = f2b(acc.w * id);
    ((ushort4*)(Bbf + (size_t)node * DIM))[q] = o;
}

// Fused layer-1 + layer-2-left
__global__ __launch_bounds__(256) void mfma_gemm_kernel(
    const ushort_t* __restrict__ xbf, const ushort_t* __restrict__ mxbf,
    const ushort_t* __restrict__ Wp, const ushort_t* __restrict__ Wp2,
    const float* __restrict__ bias,
    ushort_t* __restrict__ Hbf, ushort_t* __restrict__ Cbf, int n)
{
    __shared__ ushort_t hl[4][16 * 136];   // 16 rows x 136 (pad 8) bf16 per wave
    const int wave = threadIdx.x >> 6;
    const int lane = threadIdx.x & 63;
    const int m16  = lane & 15;
    const int quad = lane >> 4;
    const int row0 = blockIdx.x * 64 + wave * 16;
    int arow = row0 + m16;
    if (arow >= n) arow = n - 1;          // clamp; OOB rows never stored
    f32x4 acc[8];
    #pragma unroll
    for (int t = 0; t < 8; ++t) acc[t] = (f32x4){0.f, 0.f, 0.f, 0.f};
    const ushort_t* __restrict__ xrow = xbf  + (size_t)arow * DIM;
    const ushort_t* __restrict__ mrow = mxbf + (size_t)arow * DIM;
    #pragma unroll
    for (int kc = 0; kc < 8; ++kc) {
        const int kcol = (kc & 3) * 32 + quad * 8;
        const bf16x8 afrag = *(const bf16x8*)((kc < 4 ? xrow : mrow) + kcol);
        const ushort_t* __restrict__ wp = Wp + (size_t)kc * 4096 + (size_t)lane * 8;
        #pragma unroll
        for (int t = 0; t < 8; ++t) {
            const bf16x8 bfrag = *(const bf16x8*)(wp + (size_t)t * 512);
            acc[t] = __builtin_amdgcn_mfma_f32_16x16x32_bf16(afrag, bfrag, acc[t], 0, 0, 0);
        }
    }
    ushort_t* __restrict__ hw = hl[wave];
    #pragma unroll
    for (int t = 0; t < 8; ++t) {
        const int col = t * 16 + m16;
        const float bv = bias[col];
        #pragma unroll
        for (int r = 0; r < 4; ++r) {
            hw[(quad * 4 + r) * 136 + col] = f2b(fmaxf(acc[t][r] + bv, 0.f));
        }
    }
    f32x4 acc2[3];
    #pragma unroll
    for (int t = 0; t < 3; ++t) acc2[t] = (f32x4){0.f, 0.f, 0.f, 0.f};
    const bool rowok = (row0 + m16) < n;
    #pragma unroll
    for (int kc = 0; kc < 4; ++kc) {
        const bf16x8 afrag2 = *(const bf16x8*)(hw + m16 * 136 + kc * 32 + quad * 8);
        if (rowok)
            *(bf16x8*)(Hbf + (size_t)(row0 + m16) * DIM + kc * 32 + quad * 8) = afrag2;
        const ushort_t* __restrict__ wp2 = Wp2 + (size_t)kc * 1536 + (size_t)lane * 8;
        #pragma unroll
        for (int t = 0; t < 3; ++t) {
            const bf16x8 bfrag = *(const bf16x8*)(wp2 + (size_t)t * 512);
            acc2[t] = __builtin_amdgcn_mfma_f32_16x16x32_bf16(afrag2, bfrag, acc2[t], 0, 0, 0);
        }
    }
    #pragma unroll
    for (int t = 0; t < 3; ++t) {
        const int col = t * 16 + m16;
        if (col >= NCLS) continue;
        #pragma unroll
        for (int r = 0; r < 4; ++r) {
            const int row = row0 + quad * 4 + r;
            if (row < n) Cbf[(size_t)row * NCLS + col] = f2b(acc2[t][r]);
        }
    }
}

// Fused layer-2 gather + right-branch + softmax (R3-proven 4-lane edge-split)
__global__ __launch_bounds__(256) void final_kernel(
    const ushort_t* __restrict__ Hbf, const ushort_t* __restrict__ Cbf,
    const int* __restrict__ row_ptr, const int* __restrict__ eidx,
    const float* __restrict__ W, const float* __restrict__ b2,
    float* __restrict__ out, int n)
{
    __shared__ float lgs[64][41];
    const int tid  = threadIdx.x;
    const int q    = tid >> 6;
    const int lane = tid & 63;
    const int r    = lane & 3;
    const int na   = q * 16 + (lane >> 2);      // node-in-block 0..63
    const int nodeA = blockIdx.x * 64 + na;
    float lg[40];
    #pragma unroll
    for (int c = 0; c < 40; ++c) lg[c] = 0.f;
    if (nodeA < n) {
        int j  = row_ptr[nodeA] + r;
        int je = row_ptr[nodeA + 1];
        for (; j < je; j += 4) {
            int s = eidx[j];
            const uint4a* __restrict__ p = (const uint4a*)(Cbf + (size_t)s * NCLS);
            uint4a v0 = p[0], v1 = p[1], v2 = p[2], v3 = p[3], v4 = p[4];
            acc_pair(lg[0],  lg[1],  v0.x); acc_pair(lg[2],  lg[3],  v0.y);
            acc_pair(lg[4],  lg[5],  v0.z); acc_pair(lg[6],  lg[7],  v0.w);
            acc_pair(lg[8],  lg[9],  v1.x); acc_pair(lg[10], lg[11], v1.y);
            acc_pair(lg[12], lg[13], v1.z); acc_pair(lg[14], lg[15], v1.w);
            acc_pair(lg[16], lg[17], v2.x); acc_pair(lg[18], lg[19], v2.y);
            acc_pair(lg[20], lg[21], v2.z); acc_pair(lg[22], lg[23], v2.w);
            acc_pair(lg[24], lg[25], v3.x); acc_pair(lg[26], lg[27], v3.y);
            acc_pair(lg[28], lg[29], v3.z); acc_pair(lg[30], lg[31], v3.w);
            acc_pair(lg[32], lg[33], v4.x); acc_pair(lg[34], lg[35], v4.y);
            acc_pair(lg[36], lg[37], v4.z); acc_pair(lg[38], lg[39], v4.w);
        }
    }
    // transposed butterfly over 4-lane groups (no runtime array indexing)
    const bool hi1 = (lane & 1) != 0;
    float h20[20];
    #pragma unroll
    for (int i = 0; i < 20; ++i) {
        float sendv = hi1 ? lg[i] : lg[20 + i];
        float recv  = __shfl_xor(sendv, 1, 64);
        h20[i] = (hi1 ? lg[20 + i] : lg[i]) + recv;
    }
    const bool hi2 = (lane & 2) != 0;
    float h10[10];
    #pragma unroll
    for (int i = 0; i < 10; ++i) {
        float sendv = hi2 ? h20[i] : h20[10 + i];
        float recv  = __shfl_xor(sendv, 2, 64);
        h10[i] = (hi2 ? h20[10 + i] : h20[i]) + recv;
    }
    const int cbase = (hi1 ? 20 : 0) + (hi2 ? 10 : 0);
    #pragma unroll
    for (int i = 0; i < 10; ++i) lgs[na][cbase + i] = h10[i];
    __syncthreads();
    // Phase B: wave q -> cols [10q,10q+10), lane = node-in-block
    const int c0 = __builtin_amdgcn_readfirstlane(q * 10);
    const int node = blockIdx.x * 64 + lane;
    if (node < n) {
        const float dg = (float)(row_ptr[node + 1] - row_ptr[node]);
        const float id = 1.0f / fmaxf(dg, 1.0f);
        float lgd[10];
        #pragma unroll
        for (int c = 0; c < 10; ++c) lgd[c] = fmaf(lgs[lane][c0 + c], id, b2[c0 + c]);
        const ushort_t* __restrict__ h = Hbf + (size_t)node * DIM;
        for (int k = 0; k < DIM; k += 4) {
            const ushort4 hu = *(const ushort4*)(h + k);
            const float hx = b2f(hu.x), hy = b2f(hu.y), hz = b2f(hu.z), hw = b2f(hu.w);
            const float* __restrict__ w0 = W + (size_t)(k + 0) * NCLS + c0;
            const float* __restrict__ w1 = W + (size_t)(k + 1) * NCLS + c0;
            const float* __restrict__ w2 = W + (size_t)(k + 2) * NCLS + c0;
            const float* __restrict__ w3 = W + (size_t)(k + 3) * NCLS + c0;
            #pragma unroll
            for (int c = 0; c < 10; ++c) {
                float a = lgd[c];
                a = fmaf(hx, w0[c], a);
                a = fmaf(hy, w1[c], a);
                a = fmaf(hz, w2[c], a);
                a = fmaf(hw, w3[c], a);
                lgd[c] = a;
            }
        }
        #pragma unroll
        for (int c = 0; c < 10; ++c) lgs[lane][c0 + c] = lgd[c];
    }
    __syncthreads();
    if (q == 0 && node < n) {
        float v[NCLS];
        #pragma unroll
        for (int c = 0; c < NCLS; ++c) v[c] = lgs[lane][c];
        float m = v[0];
        #pragma unroll
        for (int c = 1; c < NCLS; ++c) m = fmaxf(m, v[c]);
        float s = 0.f;
        #pragma unroll
        for (int c = 0; c < NCLS; ++c) { v[c] = __expf(v[c] - m); s += v[c]; }
        const float inv = 1.0f / s;
        float* __restrict__ o = out + (size_t)node * NCLS;
        #pragma unroll
        for (int c = 0; c < NCLS; ++c) o[c] = v[c] * inv;
    }
}

extern "C" void kernel_launch(void* const* d_in, const int* in_sizes, int n_in,
                              void* d_out, int out_size, void* d_ws, size_t ws_size,
                              hipStream_t stream) {
    const float* x   = (const float*)d_in[0];
    const int*   ei  = (const int*)d_in[1];
    const float* W1l = (const float*)d_in[2];
    const float* W1r = (const float*)d_in[3];
    const float* b1  = (const float*)d_in[4];
    const float* W2l = (const float*)d_in[5];
    const float* W2r = (const float*)d_in[6];
    const float* b2  = (const float*)d_in[7];
    float* out = (float*)d_out;

    const int n = in_sizes[0] / DIM;   // 100000
    const int E = in_sizes[1] / 2;     // 1600000
    const int* src = ei;
    const int* dst = ei + E;

    // workspace layout (~105 MB):
    //   xbf (25.6M) | mxbf (25.6M) | Hbf (25.6M) | Cbf (8M) | xq (12.8M)
    //   | Wp (64K) | Wp2 (12K) | eidx[E] | deg[n] | ctr[n] | row_ptr[n+1] | binCnt[256]
    ushort_t* xbf     = (ushort_t*)d_ws;
    ushort_t* mxbf    = xbf + (size_t)n * DIM;
    ushort_t* Hbf     = mxbf + (size_t)n * DIM;
    ushort_t* Cbf     = Hbf + (size_t)n * DIM;
    unsigned* xq      = (unsigned*)(Cbf + (size_t)n * NCLS);
    ushort_t* Wp      = (ushort_t*)(xq + (size_t)n * 32);
    ushort_t* Wp2     = Wp + 256 * DIM;
    int*      eidx    = (int*)(Wp2 + 4 * 1536);
    int*      deg     = eidx + E;
    int*      ctr     = deg + n;
    int*      row_ptr = ctr + n;
    int*      binCnt  = row_ptr + (n + 1);

    // --- fused prep (cast + weight packs + binCnt zero + deg zero) ---
    const int n4 = n * 32;                       // float4 items in x
    const int cb = (n4 + 255) / 256;             // cast blocks
    const int zb = (n + 255) / 256;              // deg-zero blocks
    prep_kernel<<<cb + 153 + zb, 256, 0, stream>>>(x, xbf, xq, W1r, W1l, Wp,
                                                   W2l, Wp2, binCnt, deg, n4, cb, n);

    // --- CSR build: deg count -> rowptr scan -> direct scatter ---
    degcount_kernel<<<512, 256, 0, stream>>>(dst, deg, binCnt, E);
    rowptr_kernel  <<<NBIN, 256, 0, stream>>>(binCnt, deg, row_ptr, ctr, n);
    scatter_kernel <<<2048, 256, 0, stream>>>(src, dst, ctr, eidx, E);

    // --- layer 1 + layer-2-left ---
    {
        long long t = (long long)n * 32;
        gather128_kernel<<<(int)((t + 255) / 256), 256, 0, stream>>>(xq, row_ptr, eidx, mxbf, n);
    }
    mfma_gemm_kernel<<<(n + 63) / 64, 256, 0, stream>>>(xbf, mxbf, Wp, Wp2, b1, Hbf, Cbf, n);

    // --- layer 2: fused gather + right-branch + softmax ---
    final_kernel<<<(n + 63) / 64, 256, 0, stream>>>(Hbf, Cbf, row_ptr, eidx, W2r, b2, out, n);
}

// Round 6
// 302.590 us; speedup vs baseline: 1.3869x; 1.3869x over previous
//
#include <hip/hip_runtime.h>

#define DIM 128
#define NCLS 40
#define CPAD 64          // Cbf row stride (bf16): 128 B -> exactly one cache line
#define NBIN 256
#define BINSH 9
#define CHUNK 4096

typedef unsigned short ushort_t;
typedef __attribute__((ext_vector_type(8))) short bf16x8;
typedef __attribute__((ext_vector_type(4))) float f32x4;
typedef __attribute__((ext_vector_type(4))) unsigned uint4a;   // 16-B aligned

__device__ __forceinline__ ushort_t f2b(float f) {
    union { float f; unsigned u; } v; v.f = f;
    unsigned r = v.u + 0x7FFFu + ((v.u >> 16) & 1u);   // round-to-nearest-even
    return (ushort_t)(r >> 16);
}

__device__ __forceinline__ float b2f(ushort_t b) {
    union { unsigned u; float f; } v; v.u = ((unsigned)b) << 16;
    return v.f;
}

// accumulate 4 fp8(e4m3) values packed in w into a float4
__device__ __forceinline__ void acc_fp8x4(float4& a, int w) {
    a.x += __builtin_amdgcn_cvt_f32_fp8(w, 0);
    a.y += __builtin_amdgcn_cvt_f32_fp8(w, 1);
    a.z += __builtin_amdgcn_cvt_f32_fp8(w, 2);
    a.w += __builtin_amdgcn_cvt_f32_fp8(w, 3);
}

// add the two bf16 halves of u into a (low) and b (high); bit-identical to b2f+add
__device__ __forceinline__ void acc_pair(float& a, float& b, unsigned u) {
    union { unsigned x; float f; } lo, hi;
    lo.x = u << 16;
    hi.x = u & 0xFFFF0000u;
    a += lo.f;
    b += hi.f;
}

// ---------------- fused prep: cast + packw + packw2 + counter-zero ----------
__global__ __launch_bounds__(256) void prep_kernel(
    const float* __restrict__ x, ushort_t* __restrict__ xbf, unsigned* __restrict__ xq,
    const float* __restrict__ W1r, const float* __restrict__ W1l, ushort_t* __restrict__ Wp,
    const float* __restrict__ W2l, ushort_t* __restrict__ Wp2,
    int* __restrict__ binCnt, int* __restrict__ binCtr, int n4, int cb)
{
    const int b = blockIdx.x;
    if (b < cb) {
        int i = b * 256 + threadIdx.x;
        if (i >= n4) return;
        f32x4 v = __builtin_nontemporal_load(((const f32x4*)x) + i);
        ushort4 o;
        o.x = f2b(v.x); o.y = f2b(v.y); o.z = f2b(v.z); o.w = f2b(v.w);
        ((ushort4*)xbf)[i] = o;
        int p = __builtin_amdgcn_cvt_pk_fp8_f32(v.x, v.y, 0, false);
        p = __builtin_amdgcn_cvt_pk_fp8_f32(v.z, v.w, p, true);
        xq[i] = (unsigned)p;
    } else if (b < cb + 128) {
        int o = (b - cb) * 256 + threadIdx.x;   // 0..32767
        int j    = o & 7;
        int lane = (o >> 3) & 63;
        int t    = (o >> 9) & 7;
        int kc   = o >> 12;
        int k = kc * 32 + (lane >> 4) * 8 + j;
        int nn = t * 16 + (lane & 15);
        float v = (k < DIM) ? W1r[k * DIM + nn] : W1l[(k - DIM) * DIM + nn];
        Wp[o] = f2b(v);
    } else if (b < cb + 152) {
        int o = (b - cb - 128) * 256 + threadIdx.x;   // 0..6143
        int j    = o & 7;
        int lane = (o >> 3) & 63;
        int rem  = o >> 9;
        int t    = rem % 3;
        int kc   = rem / 3;
        int k  = kc * 32 + (lane >> 4) * 8 + j;
        int nn = t * 16 + (lane & 15);
        Wp2[o] = (nn < NCLS) ? f2b(W2l[k * NCLS + nn]) : (ushort_t)0;
    } else {
        binCnt[threadIdx.x] = 0;
        binCtr[threadIdx.x] = 0;
    }
}

// ---------------- CSR build via binned counting sort ----------------

// A1: per-bin edge counts (bin = dst >> 9)
__global__ __launch_bounds__(256) void bincount_kernel(const int* __restrict__ dst,
                                                       int* __restrict__ binCnt, int E) {
    __shared__ int hist[NBIN];
    hist[threadIdx.x] = 0;
    __syncthreads();
    const int tid = blockIdx.x * 256 + threadIdx.x;
    const int stride = gridDim.x * 256;
    for (int e = tid; e < E; e += stride)
        atomicAdd(&hist[__builtin_nontemporal_load(dst + e) >> BINSH], 1);
    __syncthreads();
    if (hist[threadIdx.x]) atomicAdd(&binCnt[threadIdx.x], hist[threadIdx.x]);
}

// A2: scatter packed (dlocal<<17|src) bucket-major. Each block locally scans
// binCnt (kills the binscan launch); binCtr is an offset-from-base counter
// (zeroed in prep). LDS-staged 4096-edge chunks; one global atomic per
// (chunk,bin) reserves a contiguous run -> ~coalesced writes.
__global__ __launch_bounds__(256) void binscatter_kernel(
    const int* __restrict__ src, const int* __restrict__ dst,
    const int* __restrict__ binCnt, int* __restrict__ binCtr,
    unsigned* __restrict__ pairs, int E)
{
    __shared__ int ss[CHUNK];    // 16 KB
    __shared__ int sd[CHUNK];    // 16 KB
    __shared__ int excl[NBIN];
    __shared__ int hist[NBIN];
    __shared__ int base[NBIN];
    __shared__ int cnt[NBIN];
    const int t = threadIdx.x;
    // local inclusive scan of binCnt -> exclusive base
    excl[t] = binCnt[t];
    __syncthreads();
    for (int off = 1; off < NBIN; off <<= 1) {
        int v = (t >= off) ? excl[t - off] : 0;
        __syncthreads();
        excl[t] += v;
        __syncthreads();
    }
    const int mybase = (t == 0) ? 0 : excl[t - 1];
    __syncthreads();
    excl[t] = mybase;
    __syncthreads();
    const int nchunk = (E + CHUNK - 1) / CHUNK;
    for (int c = blockIdx.x; c < nchunk; c += gridDim.x) {
        const int e0 = c * CHUNK;
        const int m = min(CHUNK, E - e0);
        for (int i = t; i < m; i += 256) {
            ss[i] = __builtin_nontemporal_load(src + e0 + i);
            sd[i] = __builtin_nontemporal_load(dst + e0 + i);
        }
        hist[t] = 0;
        cnt[t] = 0;
        __syncthreads();
        for (int i = t; i < m; i += 256)
            atomicAdd(&hist[sd[i] >> BINSH], 1);
        __syncthreads();
        base[t] = hist[t] ? (excl[t] + atomicAdd(&binCtr[t], hist[t])) : 0;
        __syncthreads();
        for (int i = t; i < m; i += 256) {
            int d = sd[i];
            int b = d >> BINSH;
            int off = base[b] + atomicAdd(&cnt[b], 1);
            pairs[off] = ((unsigned)(d & ((1 << BINSH) - 1)) << 17) | (unsigned)ss[i];
        }
        __syncthreads();
    }
}

// B: block b finalizes bin b (512 nodes): local binCnt scan -> lo/hi, local
// deg hist -> scan -> row_ptr, then scatters src into its PRIVATE 32KB eidx
// window (full-line writebacks).
__global__ __launch_bounds__(256) void bincsr_kernel(
    const unsigned* __restrict__ pairs, const int* __restrict__ binCnt,
    int* __restrict__ row_ptr, int* __restrict__ eidx, int n, int E)
{
    __shared__ int bs[NBIN];
    __shared__ int deg[512];
    __shared__ int sc[512];
    __shared__ int cnt[512];
    const int b  = blockIdx.x;
    const int t = threadIdx.x;
    bs[t] = binCnt[t];
    __syncthreads();
    for (int off = 1; off < NBIN; off <<= 1) {
        int v = (t >= off) ? bs[t - off] : 0;
        __syncthreads();
        bs[t] += v;
        __syncthreads();
    }
    const int lo = (b == 0) ? 0 : bs[b - 1];
    const int hi = bs[b];
    const int nlo = b << BINSH;
    deg[t] = 0; deg[t + 256] = 0;
    cnt[t] = 0; cnt[t + 256] = 0;
    __syncthreads();
    for (int e = lo + t; e < hi; e += 256)
        atomicAdd(&deg[pairs[e] >> 17], 1);
    __syncthreads();
    sc[t] = deg[t];
    sc[t + 256] = deg[t + 256];
    __syncthreads();
    for (int off = 1; off < 512; off <<= 1) {    // inclusive HS scan over 512
        int v0 = (t >= off) ? sc[t - off] : 0;
        int v1 = sc[t + 256 - off];
        __syncthreads();
        sc[t] += v0;
        sc[t + 256] += v1;
        __syncthreads();
    }
    // row_ptr[node] = lo + exclusive_prefix
    {
        int node0 = nlo + t;
        int node1 = nlo + t + 256;
        if (node0 < n) row_ptr[node0] = lo + sc[t] - deg[t];
        if (node1 < n) row_ptr[node1] = lo + sc[t + 256] - deg[t + 256];
    }
    if (b == NBIN - 1 && t == 255) row_ptr[n] = E;
    for (int e = lo + t; e < hi; e += 256) {
        unsigned p = pairs[e];
        int dl = p >> 17;
        int slot = sc[dl] - deg[dl] + atomicAdd(&cnt[dl], 1);
        eidx[lo + slot] = (int)(p & 0x1FFFFu);
    }
}

// ---------------- compute (R3-proven forms) ----------------

// mxbf[node] = mean over CSR neighbors of xq[src] (fp8 in, fp32 accum, bf16 out)
__global__ __launch_bounds__(256) void gather128_kernel(
    const unsigned* __restrict__ xq, const int* __restrict__ row_ptr,
    const int* __restrict__ eidx, ushort_t* __restrict__ Bbf, int n)
{
    int t = blockIdx.x * 256 + threadIdx.x;
    int node = t >> 5;
    if (node >= n) return;
    int q = t & 31;
    int j  = row_ptr[node];
    int je = row_ptr[node + 1];
    const float id = 1.0f / fmaxf((float)(je - j), 1.0f);
    float4 acc = make_float4(0.f, 0.f, 0.f, 0.f);
    for (; j + 3 < je; j += 4) {
        int s0 = eidx[j], s1 = eidx[j + 1], s2 = eidx[j + 2], s3 = eidx[j + 3];
        int w0 = (int)xq[(size_t)s0 * 32 + q];
        int w1 = (int)xq[(size_t)s1 * 32 + q];
        int w2 = (int)xq[(size_t)s2 * 32 + q];
        int w3 = (int)xq[(size_t)s3 * 32 + q];
        acc_fp8x4(acc, w0); acc_fp8x4(acc, w1);
        acc_fp8x4(acc, w2); acc_fp8x4(acc, w3);
    }
    for (; j < je; ++j) {
        int s0 = eidx[j];
        acc_fp8x4(acc, (int)xq[(size_t)s0 * 32 + q]);
    }
    ushort4 o;
    o.x = f2b(acc.x * id); o.y = f2b(acc.y * id);
    o.z = f2b(acc.z * id); o.w = f2b(acc.w * id);
    ((ushort4*)(Bbf + (size_t)node * DIM))[q] = o;
}

// Fused layer-1 + layer-2-left
__global__ __launch_bounds__(256) void mfma_gemm_kernel(
    const ushort_t* __restrict__ xbf, const ushort_t* __restrict__ mxbf,
    const ushort_t* __restrict__ Wp, const ushort_t* __restrict__ Wp2,
    const float* __restrict__ bias,
    ushort_t* __restrict__ Hbf, ushort_t* __restrict__ Cbf, int n)
{
    __shared__ ushort_t hl[4][16 * 136];   // 16 rows x 136 (pad 8) bf16 per wave
    const int wave = threadIdx.x >> 6;
    const int lane = threadIdx.x & 63;
    const int m16  = lane & 15;
    const int quad = lane >> 4;
    const int row0 = blockIdx.x * 64 + wave * 16;
    int arow = row0 + m16;
    if (arow >= n) arow = n - 1;          // clamp; OOB rows never stored
    f32x4 acc[8];
    #pragma unroll
    for (int t = 0; t < 8; ++t) acc[t] = (f32x4){0.f, 0.f, 0.f, 0.f};
    const ushort_t* __restrict__ xrow = xbf  + (size_t)arow * DIM;
    const ushort_t* __restrict__ mrow = mxbf + (size_t)arow * DIM;
    #pragma unroll
    for (int kc = 0; kc < 8; ++kc) {
        const int kcol = (kc & 3) * 32 + quad * 8;
        const bf16x8 afrag = *(const bf16x8*)((kc < 4 ? xrow : mrow) + kcol);
        const ushort_t* __restrict__ wp = Wp + (size_t)kc * 4096 + (size_t)lane * 8;
        #pragma unroll
        for (int t = 0; t < 8; ++t) {
            const bf16x8 bfrag = *(const bf16x8*)(wp + (size_t)t * 512);
            acc[t] = __builtin_amdgcn_mfma_f32_16x16x32_bf16(afrag, bfrag, acc[t], 0, 0, 0);
        }
    }
    ushort_t* __restrict__ hw = hl[wave];
    #pragma unroll
    for (int t = 0; t < 8; ++t) {
        const int col = t * 16 + m16;
        const float bv = bias[col];
        #pragma unroll
        for (int r = 0; r < 4; ++r) {
            hw[(quad * 4 + r) * 136 + col] = f2b(fmaxf(acc[t][r] + bv, 0.f));
        }
    }
    f32x4 acc2[3];
    #pragma unroll
    for (int t = 0; t < 3; ++t) acc2[t] = (f32x4){0.f, 0.f, 0.f, 0.f};
    const bool rowok = (row0 + m16) < n;
    #pragma unroll
    for (int kc = 0; kc < 4; ++kc) {
        const bf16x8 afrag2 = *(const bf16x8*)(hw + m16 * 136 + kc * 32 + quad * 8);
        if (rowok)
            *(bf16x8*)(Hbf + (size_t)(row0 + m16) * DIM + kc * 32 + quad * 8) = afrag2;
        const ushort_t* __restrict__ wp2 = Wp2 + (size_t)kc * 1536 + (size_t)lane * 8;
        #pragma unroll
        for (int t = 0; t < 3; ++t) {
            const bf16x8 bfrag = *(const bf16x8*)(wp2 + (size_t)t * 512);
            acc2[t] = __builtin_amdgcn_mfma_f32_16x16x32_bf16(afrag2, bfrag, acc2[t], 0, 0, 0);
        }
    }
    #pragma unroll
    for (int t = 0; t < 3; ++t) {
        const int col = t * 16 + m16;
        if (col >= NCLS) continue;
        #pragma unroll
        for (int r = 0; r < 4; ++r) {
            const int row = row0 + quad * 4 + r;
            if (row < n) Cbf[(size_t)row * CPAD + col] = f2b(acc2[t][r]);
        }
    }
}

// Fused layer-2 gather + right-branch + softmax (R3-proven 4-lane edge-split;
// Cbf rows now 128-B line-aligned -> exactly one line per edge)
__global__ __launch_bounds__(256) void final_kernel(
    const ushort_t* __restrict__ Hbf, const ushort_t* __restrict__ Cbf,
    const int* __restrict__ row_ptr, const int* __restrict__ eidx,
    const float* __restrict__ W, const float* __restrict__ b2,
    float* __restrict__ out, int n)
{
    __shared__ float lgs[64][41];
    const int tid  = threadIdx.x;
    const int q    = tid >> 6;
    const int lane = tid & 63;
    const int r    = lane & 3;
    const int na   = q * 16 + (lane >> 2);      // node-in-block 0..63
    const int nodeA = blockIdx.x * 64 + na;
    float lg[40];
    #pragma unroll
    for (int c = 0; c < 40; ++c) lg[c] = 0.f;
    if (nodeA < n) {
        int j  = row_ptr[nodeA] + r;
        int je = row_ptr[nodeA + 1];
        for (; j < je; j += 4) {
            int s = eidx[j];
            const uint4a* __restrict__ p = (const uint4a*)(Cbf + (size_t)s * CPAD);
            uint4a v0 = p[0], v1 = p[1], v2 = p[2], v3 = p[3], v4 = p[4];
            acc_pair(lg[0],  lg[1],  v0.x); acc_pair(lg[2],  lg[3],  v0.y);
            acc_pair(lg[4],  lg[5],  v0.z); acc_pair(lg[6],  lg[7],  v0.w);
            acc_pair(lg[8],  lg[9],  v1.x); acc_pair(lg[10], lg[11], v1.y);
            acc_pair(lg[12], lg[13], v1.z); acc_pair(lg[14], lg[15], v1.w);
            acc_pair(lg[16], lg[17], v2.x); acc_pair(lg[18], lg[19], v2.y);
            acc_pair(lg[20], lg[21], v2.z); acc_pair(lg[22], lg[23], v2.w);
            acc_pair(lg[24], lg[25], v3.x); acc_pair(lg[26], lg[27], v3.y);
            acc_pair(lg[28], lg[29], v3.z); acc_pair(lg[30], lg[31], v3.w);
            acc_pair(lg[32], lg[33], v4.x); acc_pair(lg[34], lg[35], v4.y);
            acc_pair(lg[36], lg[37], v4.z); acc_pair(lg[38], lg[39], v4.w);
        }
    }
    // transposed butterfly over 4-lane groups (no runtime array indexing)
    const bool hi1 = (lane & 1) != 0;
    float h20[20];
    #pragma unroll
    for (int i = 0; i < 20; ++i) {
        float sendv = hi1 ? lg[i] : lg[20 + i];
        float recv  = __shfl_xor(sendv, 1, 64);
        h20[i] = (hi1 ? lg[20 + i] : lg[i]) + recv;
    }
    const bool hi2 = (lane & 2) != 0;
    float h10[10];
    #pragma unroll
    for (int i = 0; i < 10; ++i) {
        float sendv = hi2 ? h20[i] : h20[10 + i];
        float recv  = __shfl_xor(sendv, 2, 64);
        h10[i] = (hi2 ? h20[10 + i] : h20[i]) + recv;
    }
    const int cbase = (hi1 ? 20 : 0) + (hi2 ? 10 : 0);
    #pragma unroll
    for (int i = 0; i < 10; ++i) lgs[na][cbase + i] = h10[i];
    __syncthreads();
    // Phase B: wave q -> cols [10q,10q+10), lane = node-in-block
    const int c0 = __builtin_amdgcn_readfirstlane(q * 10);
    const int node = blockIdx.x * 64 + lane;
    if (node < n) {
        const float dg = (float)(row_ptr[node + 1] - row_ptr[node]);
        const float id = 1.0f / fmaxf(dg, 1.0f);
        float lgd[10];
        #pragma unroll
        for (int c = 0; c < 10; ++c) lgd[c] = fmaf(lgs[lane][c0 + c], id, b2[c0 + c]);
        const ushort_t* __restrict__ h = Hbf + (size_t)node * DIM;
        for (int k = 0; k < DIM; k += 4) {
            const ushort4 hu = *(const ushort4*)(h + k);
            const float hx = b2f(hu.x), hy = b2f(hu.y), hz = b2f(hu.z), hw = b2f(hu.w);
            const float* __restrict__ w0 = W + (size_t)(k + 0) * NCLS + c0;
            const float* __restrict__ w1 = W + (size_t)(k + 1) * NCLS + c0;
            const float* __restrict__ w2 = W + (size_t)(k + 2) * NCLS + c0;
            const float* __restrict__ w3 = W + (size_t)(k + 3) * NCLS + c0;
            #pragma unroll
            for (int c = 0; c < 10; ++c) {
                float a = lgd[c];
                a = fmaf(hx, w0[c], a);
                a = fmaf(hy, w1[c], a);
                a = fmaf(hz, w2[c], a);
                a = fmaf(hw, w3[c], a);
                lgd[c] = a;
            }
        }
        #pragma unroll
        for (int c = 0; c < 10; ++c) lgs[lane][c0 + c] = lgd[c];
    }
    __syncthreads();
    if (q == 0 && node < n) {
        float v[NCLS];
        #pragma unroll
        for (int c = 0; c < NCLS; ++c) v[c] = lgs[lane][c];
        float m = v[0];
        #pragma unroll
        for (int c = 1; c < NCLS; ++c) m = fmaxf(m, v[c]);
        float s = 0.f;
        #pragma unroll
        for (int c = 0; c < NCLS; ++c) { v[c] = __expf(v[c] - m); s += v[c]; }
        const float inv = 1.0f / s;
        float* __restrict__ o = out + (size_t)node * NCLS;
        #pragma unroll
        for (int c = 0; c < NCLS; ++c) o[c] = v[c] * inv;
    }
}

extern "C" void kernel_launch(void* const* d_in, const int* in_sizes, int n_in,
                              void* d_out, int out_size, void* d_ws, size_t ws_size,
                              hipStream_t stream) {
    const float* x   = (const float*)d_in[0];
    const int*   ei  = (const int*)d_in[1];
    const float* W1l = (const float*)d_in[2];
    const float* W1r = (const float*)d_in[3];
    const float* b1  = (const float*)d_in[4];
    const float* W2l = (const float*)d_in[5];
    const float* W2r = (const float*)d_in[6];
    const float* b2  = (const float*)d_in[7];
    float* out = (float*)d_out;

    const int n = in_sizes[0] / DIM;   // 100000
    const int E = in_sizes[1] / 2;     // 1600000
    const int* src = ei;
    const int* dst = ei + E;

    // workspace layout (~116 MB):
    //   xbf (25.6M) | mxbf (25.6M) | Hbf (25.6M) | Cbf (12.8M, CPAD=64) | xq (12.8M)
    //   | Wp (64K) | Wp2 (12K) | eidx[E] | pairs[E] (packed int, 6.4M)
    //   | row_ptr[n+1] | binCnt[256] | binCtr[256]
    ushort_t* xbf     = (ushort_t*)d_ws;
    ushort_t* mxbf    = xbf + (size_t)n * DIM;
    ushort_t* Hbf     = mxbf + (size_t)n * DIM;
    ushort_t* Cbf     = Hbf + (size_t)n * DIM;
    unsigned* xq      = (unsigned*)(Cbf + (size_t)n * CPAD);
    ushort_t* Wp      = (ushort_t*)(xq + (size_t)n * 32);
    ushort_t* Wp2     = Wp + 256 * DIM;
    int*      eidx    = (int*)(Wp2 + 4 * 1536);
    unsigned* pairs   = (unsigned*)(eidx + E);
    int*      row_ptr = (int*)(pairs + E);
    int*      binCnt  = row_ptr + (n + 1);
    int*      binCtr  = binCnt + NBIN;

    // --- fused prep (cast + weight packs + binCnt/binCtr zero) ---
    const int n4 = n * 32;                       // float4 items in x
    const int cb = (n4 + 255) / 256;             // cast blocks
    prep_kernel<<<cb + 153, 256, 0, stream>>>(x, xbf, xq, W1r, W1l, Wp,
                                              W2l, Wp2, binCnt, binCtr, n4, cb);

    // --- CSR build via binned counting sort (binscan folded into consumers) ---
    bincount_kernel  <<<512, 256, 0, stream>>>(dst, binCnt, E);
    binscatter_kernel<<<512, 256, 0, stream>>>(src, dst, binCnt, binCtr, pairs, E);
    bincsr_kernel    <<<NBIN, 256, 0, stream>>>(pairs, binCnt, row_ptr, eidx, n, E);

    // --- layer 1 + layer-2-left ---
    {
        long long t = (long long)n * 32;
        gather128_kernel<<<(int)((t + 255) / 256), 256, 0, stream>>>(xq, row_ptr, eidx, mxbf, n);
    }
    mfma_gemm_kernel<<<(n + 63) / 64, 256, 0, stream>>>(xbf, mxbf, Wp, Wp2, b1, Hbf, Cbf, n);

    // --- layer 2: fused gather + right-branch + softmax ---
    final_kernel<<<(n + 63) / 64, 256, 0, stream>>>(Hbf, Cbf, row_ptr, eidx, W2r, b2, out, n);
}

// Round 7
// 289.644 us; speedup vs baseline: 1.4489x; 1.0447x over previous
//
#include <hip/hip_runtime.h>

#define DIM 128
#define NCLS 40
#define CPAD 64          // Cbf row stride (bf16): 128 B -> exactly one cache line
#define NBIN 256
#define BINSH 9
#define CHUNK 4096

typedef unsigned short ushort_t;
typedef __attribute__((ext_vector_type(8))) short bf16x8;
typedef __attribute__((ext_vector_type(4))) float f32x4;
typedef __attribute__((ext_vector_type(4))) unsigned uint4a;   // 16-B aligned

__device__ __forceinline__ ushort_t f2b(float f) {
    union { float f; unsigned u; } v; v.f = f;
    unsigned r = v.u + 0x7FFFu + ((v.u >> 16) & 1u);   // round-to-nearest-even
    return (ushort_t)(r >> 16);
}

__device__ __forceinline__ float b2f(ushort_t b) {
    union { unsigned u; float f; } v; v.u = ((unsigned)b) << 16;
    return v.f;
}

// accumulate 4 fp8(e4m3) values packed in w into a float4
__device__ __forceinline__ void acc_fp8x4(float4& a, int w) {
    a.x += __builtin_amdgcn_cvt_f32_fp8(w, 0);
    a.y += __builtin_amdgcn_cvt_f32_fp8(w, 1);
    a.z += __builtin_amdgcn_cvt_f32_fp8(w, 2);
    a.w += __builtin_amdgcn_cvt_f32_fp8(w, 3);
}

// add the two bf16 halves of u into a (low) and b (high); bit-identical to b2f+add
__device__ __forceinline__ void acc_pair(float& a, float& b, unsigned u) {
    union { unsigned x; float f; } lo, hi;
    lo.x = u << 16;
    hi.x = u & 0xFFFF0000u;
    a += lo.f;
    b += hi.f;
}

// accumulate one 40-col bf16 Cbf row (5 x uint4) into lg[40]
__device__ __forceinline__ void acc_row40(float* lg, uint4a v0, uint4a v1,
                                          uint4a v2, uint4a v3, uint4a v4) {
    acc_pair(lg[0],  lg[1],  v0.x); acc_pair(lg[2],  lg[3],  v0.y);
    acc_pair(lg[4],  lg[5],  v0.z); acc_pair(lg[6],  lg[7],  v0.w);
    acc_pair(lg[8],  lg[9],  v1.x); acc_pair(lg[10], lg[11], v1.y);
    acc_pair(lg[12], lg[13], v1.z); acc_pair(lg[14], lg[15], v1.w);
    acc_pair(lg[16], lg[17], v2.x); acc_pair(lg[18], lg[19], v2.y);
    acc_pair(lg[20], lg[21], v2.z); acc_pair(lg[22], lg[23], v2.w);
    acc_pair(lg[24], lg[25], v3.x); acc_pair(lg[26], lg[27], v3.y);
    acc_pair(lg[28], lg[29], v3.z); acc_pair(lg[30], lg[31], v3.w);
    acc_pair(lg[32], lg[33], v4.x); acc_pair(lg[34], lg[35], v4.y);
    acc_pair(lg[36], lg[37], v4.z); acc_pair(lg[38], lg[39], v4.w);
}

// ---------------- fused prep: cast + packw + packw2(l,r) + counter-zero -----
__global__ __launch_bounds__(256) void prep_kernel(
    const float* __restrict__ x, ushort_t* __restrict__ xbf, unsigned* __restrict__ xq,
    const float* __restrict__ W1r, const float* __restrict__ W1l, ushort_t* __restrict__ Wp,
    const float* __restrict__ W2l, ushort_t* __restrict__ Wp2,
    const float* __restrict__ W2r, ushort_t* __restrict__ Wp2r,
    int* __restrict__ binCnt, int* __restrict__ binCtr, int n4, int cb)
{
    const int b = blockIdx.x;
    if (b < cb) {
        int i = b * 256 + threadIdx.x;
        if (i >= n4) return;
        f32x4 v = __builtin_nontemporal_load(((const f32x4*)x) + i);
        ushort4 o;
        o.x = f2b(v.x); o.y = f2b(v.y); o.z = f2b(v.z); o.w = f2b(v.w);
        ((ushort4*)xbf)[i] = o;
        int p = __builtin_amdgcn_cvt_pk_fp8_f32(v.x, v.y, 0, false);
        p = __builtin_amdgcn_cvt_pk_fp8_f32(v.z, v.w, p, true);
        xq[i] = (unsigned)p;
    } else if (b < cb + 128) {
        int o = (b - cb) * 256 + threadIdx.x;   // 0..32767
        int j    = o & 7;
        int lane = (o >> 3) & 63;
        int t    = (o >> 9) & 7;
        int kc   = o >> 12;
        int k = kc * 32 + (lane >> 4) * 8 + j;
        int nn = t * 16 + (lane & 15);
        float v = (k < DIM) ? W1r[k * DIM + nn] : W1l[(k - DIM) * DIM + nn];
        Wp[o] = f2b(v);
    } else if (b < cb + 152) {
        int o = (b - cb - 128) * 256 + threadIdx.x;   // 0..6143
        int j    = o & 7;
        int lane = (o >> 3) & 63;
        int rem  = o >> 9;
        int t    = rem % 3;
        int kc   = rem / 3;
        int k  = kc * 32 + (lane >> 4) * 8 + j;
        int nn = t * 16 + (lane & 15);
        Wp2[o] = (nn < NCLS) ? f2b(W2l[k * NCLS + nn]) : (ushort_t)0;
    } else if (b < cb + 176) {
        int o = (b - cb - 152) * 256 + threadIdx.x;   // 0..6143
        int j    = o & 7;
        int lane = (o >> 3) & 63;
        int rem  = o >> 9;
        int t    = rem % 3;
        int kc   = rem / 3;
        int k  = kc * 32 + (lane >> 4) * 8 + j;
        int nn = t * 16 + (lane & 15);
        Wp2r[o] = (nn < NCLS) ? f2b(W2r[k * NCLS + nn]) : (ushort_t)0;
    } else {
        binCnt[threadIdx.x] = 0;
        binCtr[threadIdx.x] = 0;
    }
}

// ---------------- CSR build via binned counting sort ----------------

// A1: per-bin edge counts (bin = dst >> 9)
__global__ __launch_bounds__(256) void bincount_kernel(const int* __restrict__ dst,
                                                       int* __restrict__ binCnt, int E) {
    __shared__ int hist[NBIN];
    hist[threadIdx.x] = 0;
    __syncthreads();
    const int tid = blockIdx.x * 256 + threadIdx.x;
    const int stride = gridDim.x * 256;
    for (int e = tid; e < E; e += stride)
        atomicAdd(&hist[__builtin_nontemporal_load(dst + e) >> BINSH], 1);
    __syncthreads();
    if (hist[threadIdx.x]) atomicAdd(&binCnt[threadIdx.x], hist[threadIdx.x]);
}

// A2: scatter packed (dlocal<<17|src) bucket-major. Each block locally scans
// binCnt (no separate binscan launch); binCtr is offset-from-base (zeroed in
// prep). LDS-staged 4096-edge chunks; one global atomic per (chunk,bin).
__global__ __launch_bounds__(256) void binscatter_kernel(
    const int* __restrict__ src, const int* __restrict__ dst,
    const int* __restrict__ binCnt, int* __restrict__ binCtr,
    unsigned* __restrict__ pairs, int E)
{
    __shared__ int ss[CHUNK];    // 16 KB
    __shared__ int sd[CHUNK];    // 16 KB
    __shared__ int excl[NBIN];
    __shared__ int hist[NBIN];
    __shared__ int base[NBIN];
    __shared__ int cnt[NBIN];
    const int t = threadIdx.x;
    // local inclusive scan of binCnt -> exclusive base
    excl[t] = binCnt[t];
    __syncthreads();
    for (int off = 1; off < NBIN; off <<= 1) {
        int v = (t >= off) ? excl[t - off] : 0;
        __syncthreads();
        excl[t] += v;
        __syncthreads();
    }
    const int mybase = (t == 0) ? 0 : excl[t - 1];
    __syncthreads();
    excl[t] = mybase;
    __syncthreads();
    const int nchunk = (E + CHUNK - 1) / CHUNK;
    for (int c = blockIdx.x; c < nchunk; c += gridDim.x) {
        const int e0 = c * CHUNK;
        const int m = min(CHUNK, E - e0);
        for (int i = t; i < m; i += 256) {
            ss[i] = __builtin_nontemporal_load(src + e0 + i);
            sd[i] = __builtin_nontemporal_load(dst + e0 + i);
        }
        hist[t] = 0;
        cnt[t] = 0;
        __syncthreads();
        for (int i = t; i < m; i += 256)
            atomicAdd(&hist[sd[i] >> BINSH], 1);
        __syncthreads();
        base[t] = hist[t] ? (excl[t] + atomicAdd(&binCtr[t], hist[t])) : 0;
        __syncthreads();
        for (int i = t; i < m; i += 256) {
            int d = sd[i];
            int b = d >> BINSH;
            int off = base[b] + atomicAdd(&cnt[b], 1);
            pairs[off] = ((unsigned)(d & ((1 << BINSH) - 1)) << 17) | (unsigned)ss[i];
        }
        __syncthreads();
    }
}

// B: block b finalizes bin b (512 nodes): local binCnt scan -> lo/hi, local
// deg hist -> scan -> row_ptr, then scatters src into its PRIVATE 32KB eidx
// window (full-line writebacks).
__global__ __launch_bounds__(256) void bincsr_kernel(
    const unsigned* __restrict__ pairs, const int* __restrict__ binCnt,
    int* __restrict__ row_ptr, int* __restrict__ eidx, int n, int E)
{
    __shared__ int bs[NBIN];
    __shared__ int deg[512];
    __shared__ int sc[512];
    __shared__ int cnt[512];
    const int b  = blockIdx.x;
    const int t = threadIdx.x;
    bs[t] = binCnt[t];
    __syncthreads();
    for (int off = 1; off < NBIN; off <<= 1) {
        int v = (t >= off) ? bs[t - off] : 0;
        __syncthreads();
        bs[t] += v;
        __syncthreads();
    }
    const int lo = (b == 0) ? 0 : bs[b - 1];
    const int hi = bs[b];
    const int nlo = b << BINSH;
    deg[t] = 0; deg[t + 256] = 0;
    cnt[t] = 0; cnt[t + 256] = 0;
    __syncthreads();
    for (int e = lo + t; e < hi; e += 256)
        atomicAdd(&deg[pairs[e] >> 17], 1);
    __syncthreads();
    sc[t] = deg[t];
    sc[t + 256] = deg[t + 256];
    __syncthreads();
    for (int off = 1; off < 512; off <<= 1) {    // inclusive HS scan over 512
        int v0 = (t >= off) ? sc[t - off] : 0;
        int v1 = sc[t + 256 - off];
        __syncthreads();
        sc[t] += v0;
        sc[t + 256] += v1;
        __syncthreads();
    }
    // row_ptr[node] = lo + exclusive_prefix
    {
        int node0 = nlo + t;
        int node1 = nlo + t + 256;
        if (node0 < n) row_ptr[node0] = lo + sc[t] - deg[t];
        if (node1 < n) row_ptr[node1] = lo + sc[t + 256] - deg[t + 256];
    }
    if (b == NBIN - 1 && t == 255) row_ptr[n] = E;
    for (int e = lo + t; e < hi; e += 256) {
        unsigned p = pairs[e];
        int dl = p >> 17;
        int slot = sc[dl] - deg[dl] + atomicAdd(&cnt[dl], 1);
        eidx[lo + slot] = (int)(p & 0x1FFFFu);
    }
}

// ---------------- compute ----------------

// mxbf[node] = mean over CSR neighbors of xq[src] (fp8 in, fp32 accum, bf16 out)
__global__ __launch_bounds__(256) void gather128_kernel(
    const unsigned* __restrict__ xq, const int* __restrict__ row_ptr,
    const int* __restrict__ eidx, ushort_t* __restrict__ Bbf, int n)
{
    int t = blockIdx.x * 256 + threadIdx.x;
    int node = t >> 5;
    if (node >= n) return;
    int q = t & 31;
    int j  = row_ptr[node];
    int je = row_ptr[node + 1];
    const float id = 1.0f / fmaxf((float)(je - j), 1.0f);
    float4 acc = make_float4(0.f, 0.f, 0.f, 0.f);
    for (; j + 3 < je; j += 4) {
        int s0 = eidx[j], s1 = eidx[j + 1], s2 = eidx[j + 2], s3 = eidx[j + 3];
        int w0 = (int)xq[(size_t)s0 * 32 + q];
        int w1 = (int)xq[(size_t)s1 * 32 + q];
        int w2 = (int)xq[(size_t)s2 * 32 + q];
        int w3 = (int)xq[(size_t)s3 * 32 + q];
        acc_fp8x4(acc, w0); acc_fp8x4(acc, w1);
        acc_fp8x4(acc, w2); acc_fp8x4(acc, w3);
    }
    for (; j < je; ++j) {
        int s0 = eidx[j];
        acc_fp8x4(acc, (int)xq[(size_t)s0 * 32 + q]);
    }
    ushort4 o;
    o.x = f2b(acc.x * id); o.y = f2b(acc.y * id);
    o.z = f2b(acc.z * id); o.w = f2b(acc.w * id);
    ((ushort4*)(Bbf + (size_t)node * DIM))[q] = o;
}

// Fused layer-1 + layer-2-left + layer-2-right.
// Computes h (ReLU(x@W1r + mean@W1l + b1)) per 16-row wave tile in LDS, then
// BOTH class-space projections with the same A-fragment: Cbf = h@W2l (bf16,
// gathered by final) and Dfl = h@W2r (fp32, final's dense branch). No Hbf.
__global__ __launch_bounds__(256) void mfma_gemm_kernel(
    const ushort_t* __restrict__ xbf, const ushort_t* __restrict__ mxbf,
    const ushort_t* __restrict__ Wp, const ushort_t* __restrict__ Wp2,
    const ushort_t* __restrict__ Wp2r, const float* __restrict__ bias,
    ushort_t* __restrict__ Cbf, float* __restrict__ Dfl, int n)
{
    __shared__ ushort_t hl[4][16 * 136];   // 16 rows x 136 (pad 8) bf16 per wave
    const int wave = threadIdx.x >> 6;
    const int lane = threadIdx.x & 63;
    const int m16  = lane & 15;
    const int quad = lane >> 4;
    const int row0 = blockIdx.x * 64 + wave * 16;
    int arow = row0 + m16;
    if (arow >= n) arow = n - 1;          // clamp; OOB rows never stored
    f32x4 acc[8];
    #pragma unroll
    for (int t = 0; t < 8; ++t) acc[t] = (f32x4){0.f, 0.f, 0.f, 0.f};
    const ushort_t* __restrict__ xrow = xbf  + (size_t)arow * DIM;
    const ushort_t* __restrict__ mrow = mxbf + (size_t)arow * DIM;
    #pragma unroll
    for (int kc = 0; kc < 8; ++kc) {
        const int kcol = (kc & 3) * 32 + quad * 8;
        const bf16x8 afrag = *(const bf16x8*)((kc < 4 ? xrow : mrow) + kcol);
        const ushort_t* __restrict__ wp = Wp + (size_t)kc * 4096 + (size_t)lane * 8;
        #pragma unroll
        for (int t = 0; t < 8; ++t) {
            const bf16x8 bfrag = *(const bf16x8*)(wp + (size_t)t * 512);
            acc[t] = __builtin_amdgcn_mfma_f32_16x16x32_bf16(afrag, bfrag, acc[t], 0, 0, 0);
        }
    }
    ushort_t* __restrict__ hw = hl[wave];
    #pragma unroll
    for (int t = 0; t < 8; ++t) {
        const int col = t * 16 + m16;
        const float bv = bias[col];
        #pragma unroll
        for (int r = 0; r < 4; ++r) {
            hw[(quad * 4 + r) * 136 + col] = f2b(fmaxf(acc[t][r] + bv, 0.f));
        }
    }
    f32x4 acc2[3];
    f32x4 acc3[3];
    #pragma unroll
    for (int t = 0; t < 3; ++t) {
        acc2[t] = (f32x4){0.f, 0.f, 0.f, 0.f};
        acc3[t] = (f32x4){0.f, 0.f, 0.f, 0.f};
    }
    #pragma unroll
    for (int kc = 0; kc < 4; ++kc) {
        const bf16x8 afrag2 = *(const bf16x8*)(hw + m16 * 136 + kc * 32 + quad * 8);
        const ushort_t* __restrict__ wp2  = Wp2  + (size_t)kc * 1536 + (size_t)lane * 8;
        const ushort_t* __restrict__ wp2r = Wp2r + (size_t)kc * 1536 + (size_t)lane * 8;
        #pragma unroll
        for (int t = 0; t < 3; ++t) {
            const bf16x8 bfrag  = *(const bf16x8*)(wp2  + (size_t)t * 512);
            const bf16x8 bfragr = *(const bf16x8*)(wp2r + (size_t)t * 512);
            acc2[t] = __builtin_amdgcn_mfma_f32_16x16x32_bf16(afrag2, bfrag,  acc2[t], 0, 0, 0);
            acc3[t] = __builtin_amdgcn_mfma_f32_16x16x32_bf16(afrag2, bfragr, acc3[t], 0, 0, 0);
        }
    }
    #pragma unroll
    for (int t = 0; t < 3; ++t) {
        const int col = t * 16 + m16;
        if (col >= NCLS) continue;
        #pragma unroll
        for (int r = 0; r < 4; ++r) {
            const int row = row0 + quad * 4 + r;
            if (row < n) {
                Cbf[(size_t)row * CPAD + col] = f2b(acc2[t][r]);
                Dfl[(size_t)row * NCLS + col] = acc3[t][r];
            }
        }
    }
}

// Fused layer-2 gather + softmax. Phase A: 4 lanes per node (edge-split),
// unrolled x2 -> 10 line-aligned loads in flight, butterfly 40->20->10.
// Phase B: lg = fmaf(gather, id, b2) + Dfl (dense branch precomputed by gemm).
__global__ __launch_bounds__(256) void final_kernel(
    const float* __restrict__ Dfl, const ushort_t* __restrict__ Cbf,
    const int* __restrict__ row_ptr, const int* __restrict__ eidx,
    const float* __restrict__ b2,
    float* __restrict__ out, int n)
{
    __shared__ float lgs[64][41];
    const int tid  = threadIdx.x;
    const int q    = tid >> 6;
    const int lane = tid & 63;
    const int r    = lane & 3;
    const int na   = q * 16 + (lane >> 2);      // node-in-block 0..63
    const int nodeA = blockIdx.x * 64 + na;
    float lg[40];
    #pragma unroll
    for (int c = 0; c < 40; ++c) lg[c] = 0.f;
    if (nodeA < n) {
        int j  = row_ptr[nodeA] + r;
        int je = row_ptr[nodeA + 1];
        for (; j + 4 < je; j += 8) {
            int s0 = eidx[j];
            int s1 = eidx[j + 4];
            const uint4a* __restrict__ p0 = (const uint4a*)(Cbf + (size_t)s0 * CPAD);
            const uint4a* __restrict__ p1 = (const uint4a*)(Cbf + (size_t)s1 * CPAD);
            uint4a a0 = p0[0], a1 = p0[1], a2 = p0[2], a3 = p0[3], a4 = p0[4];
            uint4a c0v = p1[0], c1 = p1[1], c2 = p1[2], c3 = p1[3], c4 = p1[4];
            acc_row40(lg, a0, a1, a2, a3, a4);
            acc_row40(lg, c0v, c1, c2, c3, c4);
        }
        if (j < je) {
            const uint4a* __restrict__ p0 = (const uint4a*)(Cbf + (size_t)eidx[j] * CPAD);
            uint4a a0 = p0[0], a1 = p0[1], a2 = p0[2], a3 = p0[3], a4 = p0[4];
            acc_row40(lg, a0, a1, a2, a3, a4);
        }
    }
    // transposed butterfly over 4-lane groups (no runtime array indexing)
    const bool hi1 = (lane & 1) != 0;
    float h20[20];
    #pragma unroll
    for (int i = 0; i < 20; ++i) {
        float sendv = hi1 ? lg[i] : lg[20 + i];
        float recv  = __shfl_xor(sendv, 1, 64);
        h20[i] = (hi1 ? lg[20 + i] : lg[i]) + recv;
    }
    const bool hi2 = (lane & 2) != 0;
    float h10[10];
    #pragma unroll
    for (int i = 0; i < 10; ++i) {
        float sendv = hi2 ? h20[i] : h20[10 + i];
        float recv  = __shfl_xor(sendv, 2, 64);
        h10[i] = (hi2 ? h20[10 + i] : h20[i]) + recv;
    }
    const int cbase = (hi1 ? 20 : 0) + (hi2 ? 10 : 0);
    #pragma unroll
    for (int i = 0; i < 10; ++i) lgs[na][cbase + i] = h10[i];
    __syncthreads();
    // Phase B: wave q -> cols [10q,10q+10), lane = node-in-block
    const int c0 = __builtin_amdgcn_readfirstlane(q * 10);
    const int node = blockIdx.x * 64 + lane;
    if (node < n) {
        const float dg = (float)(row_ptr[node + 1] - row_ptr[node]);
        const float id = 1.0f / fmaxf(dg, 1.0f);
        const float* __restrict__ drow = Dfl + (size_t)node * NCLS + c0;
        #pragma unroll
        for (int c = 0; c < 10; ++c)
            lgs[lane][c0 + c] = fmaf(lgs[lane][c0 + c], id, b2[c0 + c]) + drow[c];
    }
    __syncthreads();
    if (q == 0 && node < n) {
        float v[NCLS];
        #pragma unroll
        for (int c = 0; c < NCLS; ++c) v[c] = lgs[lane][c];
        float m = v[0];
        #pragma unroll
        for (int c = 1; c < NCLS; ++c) m = fmaxf(m, v[c]);
        float s = 0.f;
        #pragma unroll
        for (int c = 0; c < NCLS; ++c) { v[c] = __expf(v[c] - m); s += v[c]; }
        const float inv = 1.0f / s;
        float* __restrict__ o = out + (size_t)node * NCLS;
        #pragma unroll
        for (int c = 0; c < NCLS; ++c) o[c] = v[c] * inv;
    }
}

extern "C" void kernel_launch(void* const* d_in, const int* in_sizes, int n_in,
                              void* d_out, int out_size, void* d_ws, size_t ws_size,
                              hipStream_t stream) {
    const float* x   = (const float*)d_in[0];
    const int*   ei  = (const int*)d_in[1];
    const float* W1l = (const float*)d_in[2];
    const float* W1r = (const float*)d_in[3];
    const float* b1  = (const float*)d_in[4];
    const float* W2l = (const float*)d_in[5];
    const float* W2r = (const float*)d_in[6];
    const float* b2  = (const float*)d_in[7];
    float* out = (float*)d_out;

    const int n = in_sizes[0] / DIM;   // 100000
    const int E = in_sizes[1] / 2;     // 1600000
    const int* src = ei;
    const int* dst = ei + E;

    // workspace layout (~105 MB):
    //   xbf (25.6M) | mxbf (25.6M) | Dfl (16M fp32) | Cbf (12.8M, CPAD=64)
    //   | xq (12.8M) | Wp (64K) | Wp2 (12K) | Wp2r (12K) | eidx[E]
    //   | pairs[E] (packed int, 6.4M) | row_ptr[n+1] | binCnt[256] | binCtr[256]
    ushort_t* xbf     = (ushort_t*)d_ws;
    ushort_t* mxbf    = xbf + (size_t)n * DIM;
    float*    Dfl     = (float*)(mxbf + (size_t)n * DIM);
    ushort_t* Cbf     = (ushort_t*)(Dfl + (size_t)n * NCLS);
    unsigned* xq      = (unsigned*)(Cbf + (size_t)n * CPAD);
    ushort_t* Wp      = (ushort_t*)(xq + (size_t)n * 32);
    ushort_t* Wp2     = Wp + 256 * DIM;
    ushort_t* Wp2r    = Wp2 + 4 * 1536;
    int*      eidx    = (int*)(Wp2r + 4 * 1536);
    unsigned* pairs   = (unsigned*)(eidx + E);
    int*      row_ptr = (int*)(pairs + E);
    int*      binCnt  = row_ptr + (n + 1);
    int*      binCtr  = binCnt + NBIN;

    // --- fused prep (cast + weight packs + binCnt/binCtr zero) ---
    const int n4 = n * 32;                       // float4 items in x
    const int cb = (n4 + 255) / 256;             // cast blocks
    prep_kernel<<<cb + 177, 256, 0, stream>>>(x, xbf, xq, W1r, W1l, Wp,
                                              W2l, Wp2, W2r, Wp2r,
                                              binCnt, binCtr, n4, cb);

    // --- CSR build via binned counting sort ---
    bincount_kernel  <<<512, 256, 0, stream>>>(dst, binCnt, E);
    binscatter_kernel<<<512, 256, 0, stream>>>(src, dst, binCnt, binCtr, pairs, E);
    bincsr_kernel    <<<NBIN, 256, 0, stream>>>(pairs, binCnt, row_ptr, eidx, n, E);

    // --- layer 1 + layer-2 projections ---
    {
        long long t = (long long)n * 32;
        gather128_kernel<<<(int)((t + 255) / 256), 256, 0, stream>>>(xq, row_ptr, eidx, mxbf, n);
    }
    mfma_gemm_kernel<<<(n + 63) / 64, 256, 0, stream>>>(xbf, mxbf, Wp, Wp2, Wp2r,
                                                        b1, Cbf, Dfl, n);

    // --- layer 2: fused gather + softmax ---
    final_kernel<<<(n + 63) / 64, 256, 0, stream>>>(Dfl, Cbf, row_ptr, eidx, b2, out, n);
}

// Round 8
// 281.171 us; speedup vs baseline: 1.4925x; 1.0301x over previous
//
#include <hip/hip_runtime.h>

#define DIM 128
#define NCLS 40
#define CPAD 64          // Cbf row stride (bf16): 128 B -> exactly one cache line
#define NBIN 256
#define BINSH 9
#define CHUNK 4096

typedef unsigned short ushort_t;
typedef __attribute__((ext_vector_type(8))) short bf16x8;
typedef __attribute__((ext_vector_type(4))) float f32x4;
typedef __attribute__((ext_vector_type(2))) float f32x2;
typedef __attribute__((ext_vector_type(4))) unsigned uint4a;   // 16-B aligned

__device__ __forceinline__ ushort_t f2b(float f) {
    union { float f; unsigned u; } v; v.f = f;
    unsigned r = v.u + 0x7FFFu + ((v.u >> 16) & 1u);   // round-to-nearest-even
    return (ushort_t)(r >> 16);
}

__device__ __forceinline__ float b2f(ushort_t b) {
    union { unsigned u; float f; } v; v.u = ((unsigned)b) << 16;
    return v.f;
}

// accumulate 4 fp8(e4m3) values packed in w into a float4 (packed cvt: 2/instr)
__device__ __forceinline__ void acc_fp8x4(float4& a, int w) {
    f32x2 lo = __builtin_amdgcn_cvt_pk_f32_fp8(w, false);
    f32x2 hi = __builtin_amdgcn_cvt_pk_f32_fp8(w, true);
    a.x += lo.x; a.y += lo.y; a.z += hi.x; a.w += hi.y;
}

// add the two bf16 halves of u into a (low) and b (high); bit-identical to b2f+add
__device__ __forceinline__ void acc_pair(float& a, float& b, unsigned u) {
    union { unsigned x; float f; } lo, hi;
    lo.x = u << 16;
    hi.x = u & 0xFFFF0000u;
    a += lo.f;
    b += hi.f;
}

// accumulate one 40-col bf16 Cbf row (5 x uint4) into lg[40]
__device__ __forceinline__ void acc_row40(float* lg, uint4a v0, uint4a v1,
                                          uint4a v2, uint4a v3, uint4a v4) {
    acc_pair(lg[0],  lg[1],  v0.x); acc_pair(lg[2],  lg[3],  v0.y);
    acc_pair(lg[4],  lg[5],  v0.z); acc_pair(lg[6],  lg[7],  v0.w);
    acc_pair(lg[8],  lg[9],  v1.x); acc_pair(lg[10], lg[11], v1.y);
    acc_pair(lg[12], lg[13], v1.z); acc_pair(lg[14], lg[15], v1.w);
    acc_pair(lg[16], lg[17], v2.x); acc_pair(lg[18], lg[19], v2.y);
    acc_pair(lg[20], lg[21], v2.z); acc_pair(lg[22], lg[23], v2.w);
    acc_pair(lg[24], lg[25], v3.x); acc_pair(lg[26], lg[27], v3.y);
    acc_pair(lg[28], lg[29], v3.z); acc_pair(lg[30], lg[31], v3.w);
    acc_pair(lg[32], lg[33], v4.x); acc_pair(lg[34], lg[35], v4.y);
    acc_pair(lg[36], lg[37], v4.z); acc_pair(lg[38], lg[39], v4.w);
}

// -- fused prep: cast + packw + packw2(l,r) + bincount (binCnt pre-zeroed) ---
__global__ __launch_bounds__(256) void prep_kernel(
    const float* __restrict__ x, ushort_t* __restrict__ xbf, unsigned* __restrict__ xq,
    const float* __restrict__ W1r, const float* __restrict__ W1l, ushort_t* __restrict__ Wp,
    const float* __restrict__ W2l, ushort_t* __restrict__ Wp2,
    const float* __restrict__ W2r, ushort_t* __restrict__ Wp2r,
    const int* __restrict__ dst, int* __restrict__ binCnt, int E, int n4, int cb)
{
    const int b = blockIdx.x;
    if (b < cb) {
        int i = b * 256 + threadIdx.x;
        if (i >= n4) return;
        f32x4 v = __builtin_nontemporal_load(((const f32x4*)x) + i);
        ushort4 o;
        o.x = f2b(v.x); o.y = f2b(v.y); o.z = f2b(v.z); o.w = f2b(v.w);
        ((ushort4*)xbf)[i] = o;
        int p = __builtin_amdgcn_cvt_pk_fp8_f32(v.x, v.y, 0, false);
        p = __builtin_amdgcn_cvt_pk_fp8_f32(v.z, v.w, p, true);
        xq[i] = (unsigned)p;
    } else if (b < cb + 128) {
        int o = (b - cb) * 256 + threadIdx.x;   // 0..32767
        int j    = o & 7;
        int lane = (o >> 3) & 63;
        int t    = (o >> 9) & 7;
        int kc   = o >> 12;
        int k = kc * 32 + (lane >> 4) * 8 + j;
        int nn = t * 16 + (lane & 15);
        float v = (k < DIM) ? W1r[k * DIM + nn] : W1l[(k - DIM) * DIM + nn];
        Wp[o] = f2b(v);
    } else if (b < cb + 152) {
        int o = (b - cb - 128) * 256 + threadIdx.x;   // 0..6143
        int j    = o & 7;
        int lane = (o >> 3) & 63;
        int rem  = o >> 9;
        int t    = rem % 3;
        int kc   = rem / 3;
        int k  = kc * 32 + (lane >> 4) * 8 + j;
        int nn = t * 16 + (lane & 15);
        Wp2[o] = (nn < NCLS) ? f2b(W2l[k * NCLS + nn]) : (ushort_t)0;
    } else if (b < cb + 176) {
        int o = (b - cb - 152) * 256 + threadIdx.x;   // 0..6143
        int j    = o & 7;
        int lane = (o >> 3) & 63;
        int rem  = o >> 9;
        int t    = rem % 3;
        int kc   = rem / 3;
        int k  = kc * 32 + (lane >> 4) * 8 + j;
        int nn = t * 16 + (lane & 15);
        Wp2r[o] = (nn < NCLS) ? f2b(W2r[k * NCLS + nn]) : (ushort_t)0;
    } else {
        // bincount tail blocks (binCnt zeroed by hipMemsetAsync before launch)
        __shared__ int hist[NBIN];
        hist[threadIdx.x] = 0;
        __syncthreads();
        const int nb = (int)gridDim.x - (cb + 176);
        const int bi = b - (cb + 176);
        const int tid = bi * 256 + threadIdx.x;
        const int stride = nb * 256;
        for (int e = tid; e < E; e += stride)
            atomicAdd(&hist[__builtin_nontemporal_load(dst + e) >> BINSH], 1);
        __syncthreads();
        if (hist[threadIdx.x]) atomicAdd(&binCnt[threadIdx.x], hist[threadIdx.x]);
    }
}

// ---------------- CSR build via binned counting sort ----------------

// A2: scatter packed (dlocal<<17|src) bucket-major. Each block locally scans
// binCnt; binCtr is offset-from-base (pre-zeroed). LDS-staged 4096-edge
// chunks; one global atomic per (chunk,bin).
__global__ __launch_bounds__(256) void binscatter_kernel(
    const int* __restrict__ src, const int* __restrict__ dst,
    const int* __restrict__ binCnt, int* __restrict__ binCtr,
    unsigned* __restrict__ pairs, int E)
{
    __shared__ int ss[CHUNK];    // 16 KB
    __shared__ int sd[CHUNK];    // 16 KB
    __shared__ int excl[NBIN];
    __shared__ int hist[NBIN];
    __shared__ int base[NBIN];
    __shared__ int cnt[NBIN];
    const int t = threadIdx.x;
    // local inclusive scan of binCnt -> exclusive base
    excl[t] = binCnt[t];
    __syncthreads();
    for (int off = 1; off < NBIN; off <<= 1) {
        int v = (t >= off) ? excl[t - off] : 0;
        __syncthreads();
        excl[t] += v;
        __syncthreads();
    }
    const int mybase = (t == 0) ? 0 : excl[t - 1];
    __syncthreads();
    excl[t] = mybase;
    __syncthreads();
    const int nchunk = (E + CHUNK - 1) / CHUNK;
    for (int c = blockIdx.x; c < nchunk; c += gridDim.x) {
        const int e0 = c * CHUNK;
        const int m = min(CHUNK, E - e0);
        for (int i = t; i < m; i += 256) {
            ss[i] = __builtin_nontemporal_load(src + e0 + i);
            sd[i] = __builtin_nontemporal_load(dst + e0 + i);
        }
        hist[t] = 0;
        cnt[t] = 0;
        __syncthreads();
        for (int i = t; i < m; i += 256)
            atomicAdd(&hist[sd[i] >> BINSH], 1);
        __syncthreads();
        base[t] = hist[t] ? (excl[t] + atomicAdd(&binCtr[t], hist[t])) : 0;
        __syncthreads();
        for (int i = t; i < m; i += 256) {
            int d = sd[i];
            int b = d >> BINSH;
            int off = base[b] + atomicAdd(&cnt[b], 1);
            pairs[off] = ((unsigned)(d & ((1 << BINSH) - 1)) << 17) | (unsigned)ss[i];
        }
        __syncthreads();
    }
}

// B: block b finalizes bin b (512 nodes): local binCnt scan -> lo/hi, local
// deg hist -> scan -> row_ptr, then scatters src into its PRIVATE 32KB eidx
// window (full-line writebacks).
__global__ __launch_bounds__(256) void bincsr_kernel(
    const unsigned* __restrict__ pairs, const int* __restrict__ binCnt,
    int* __restrict__ row_ptr, int* __restrict__ eidx, int n, int E)
{
    __shared__ int bs[NBIN];
    __shared__ int deg[512];
    __shared__ int sc[512];
    __shared__ int cnt[512];
    const int b  = blockIdx.x;
    const int t = threadIdx.x;
    bs[t] = binCnt[t];
    __syncthreads();
    for (int off = 1; off < NBIN; off <<= 1) {
        int v = (t >= off) ? bs[t - off] : 0;
        __syncthreads();
        bs[t] += v;
        __syncthreads();
    }
    const int lo = (b == 0) ? 0 : bs[b - 1];
    const int hi = bs[b];
    const int nlo = b << BINSH;
    deg[t] = 0; deg[t + 256] = 0;
    cnt[t] = 0; cnt[t + 256] = 0;
    __syncthreads();
    for (int e = lo + t; e < hi; e += 256)
        atomicAdd(&deg[pairs[e] >> 17], 1);
    __syncthreads();
    sc[t] = deg[t];
    sc[t + 256] = deg[t + 256];
    __syncthreads();
    for (int off = 1; off < 512; off <<= 1) {    // inclusive HS scan over 512
        int v0 = (t >= off) ? sc[t - off] : 0;
        int v1 = sc[t + 256 - off];
        __syncthreads();
        sc[t] += v0;
        sc[t + 256] += v1;
        __syncthreads();
    }
    // row_ptr[node] = lo + exclusive_prefix
    {
        int node0 = nlo + t;
        int node1 = nlo + t + 256;
        if (node0 < n) row_ptr[node0] = lo + sc[t] - deg[t];
        if (node1 < n) row_ptr[node1] = lo + sc[t + 256] - deg[t + 256];
    }
    if (b == NBIN - 1 && t == 255) row_ptr[n] = E;
    for (int e = lo + t; e < hi; e += 256) {
        unsigned p = pairs[e];
        int dl = p >> 17;
        int slot = sc[dl] - deg[dl] + atomicAdd(&cnt[dl], 1);
        eidx[lo + slot] = (int)(p & 0x1FFFFu);
    }
}

// ---------------- compute ----------------

// mxbf[node] = mean over CSR neighbors of xq[src] (fp8 in, fp32 accum, bf16 out)
// x8 unroll (8 row-loads in flight) + packed fp8 converts. Per-accumulator
// addition order identical to the x4 form -> bit-identical results.
__global__ __launch_bounds__(256) void gather128_kernel(
    const unsigned* __restrict__ xq, const int* __restrict__ row_ptr,
    const int* __restrict__ eidx, ushort_t* __restrict__ Bbf, int n)
{
    int t = blockIdx.x * 256 + threadIdx.x;
    int node = t >> 5;
    if (node >= n) return;
    int q = t & 31;
    int j  = row_ptr[node];
    int je = row_ptr[node + 1];
    const float id = 1.0f / fmaxf((float)(je - j), 1.0f);
    float4 acc = make_float4(0.f, 0.f, 0.f, 0.f);
    for (; j + 7 < je; j += 8) {
        int s0 = eidx[j],     s1 = eidx[j + 1], s2 = eidx[j + 2], s3 = eidx[j + 3];
        int s4 = eidx[j + 4], s5 = eidx[j + 5], s6 = eidx[j + 6], s7 = eidx[j + 7];
        int w0 = (int)xq[(size_t)s0 * 32 + q];
        int w1 = (int)xq[(size_t)s1 * 32 + q];
        int w2 = (int)xq[(size_t)s2 * 32 + q];
        int w3 = (int)xq[(size_t)s3 * 32 + q];
        int w4 = (int)xq[(size_t)s4 * 32 + q];
        int w5 = (int)xq[(size_t)s5 * 32 + q];
        int w6 = (int)xq[(size_t)s6 * 32 + q];
        int w7 = (int)xq[(size_t)s7 * 32 + q];
        acc_fp8x4(acc, w0); acc_fp8x4(acc, w1);
        acc_fp8x4(acc, w2); acc_fp8x4(acc, w3);
        acc_fp8x4(acc, w4); acc_fp8x4(acc, w5);
        acc_fp8x4(acc, w6); acc_fp8x4(acc, w7);
    }
    for (; j + 3 < je; j += 4) {
        int s0 = eidx[j], s1 = eidx[j + 1], s2 = eidx[j + 2], s3 = eidx[j + 3];
        int w0 = (int)xq[(size_t)s0 * 32 + q];
        int w1 = (int)xq[(size_t)s1 * 32 + q];
        int w2 = (int)xq[(size_t)s2 * 32 + q];
        int w3 = (int)xq[(size_t)s3 * 32 + q];
        acc_fp8x4(acc, w0); acc_fp8x4(acc, w1);
        acc_fp8x4(acc, w2); acc_fp8x4(acc, w3);
    }
    for (; j < je; ++j) {
        int s0 = eidx[j];
        acc_fp8x4(acc, (int)xq[(size_t)s0 * 32 + q]);
    }
    ushort4 o;
    o.x = f2b(acc.x * id); o.y = f2b(acc.y * id);
    o.z = f2b(acc.z * id); o.w = f2b(acc.w * id);
    ((ushort4*)(Bbf + (size_t)node * DIM))[q] = o;
}

// Fused layer-1 + layer-2-left + layer-2-right.
// Computes h (ReLU(x@W1r + mean@W1l + b1)) per 16-row wave tile in LDS, then
// BOTH class-space projections with the same A-fragment: Cbf = h@W2l (bf16,
// gathered by final) and Dfl = h@W2r (fp32, final's dense branch). No Hbf.
__global__ __launch_bounds__(256) void mfma_gemm_kernel(
    const ushort_t* __restrict__ xbf, const ushort_t* __restrict__ mxbf,
    const ushort_t* __restrict__ Wp, const ushort_t* __restrict__ Wp2,
    const ushort_t* __restrict__ Wp2r, const float* __restrict__ bias,
    ushort_t* __restrict__ Cbf, float* __restrict__ Dfl, int n)
{
    __shared__ ushort_t hl[4][16 * 136];   // 16 rows x 136 (pad 8) bf16 per wave
    const int wave = threadIdx.x >> 6;
    const int lane = threadIdx.x & 63;
    const int m16  = lane & 15;
    const int quad = lane >> 4;
    const int row0 = blockIdx.x * 64 + wave * 16;
    int arow = row0 + m16;
    if (arow >= n) arow = n - 1;          // clamp; OOB rows never stored
    f32x4 acc[8];
    #pragma unroll
    for (int t = 0; t < 8; ++t) acc[t] = (f32x4){0.f, 0.f, 0.f, 0.f};
    const ushort_t* __restrict__ xrow = xbf  + (size_t)arow * DIM;
    const ushort_t* __restrict__ mrow = mxbf + (size_t)arow * DIM;
    #pragma unroll
    for (int kc = 0; kc < 8; ++kc) {
        const int kcol = (kc & 3) * 32 + quad * 8;
        const bf16x8 afrag = *(const bf16x8*)((kc < 4 ? xrow : mrow) + kcol);
        const ushort_t* __restrict__ wp = Wp + (size_t)kc * 4096 + (size_t)lane * 8;
        #pragma unroll
        for (int t = 0; t < 8; ++t) {
            const bf16x8 bfrag = *(const bf16x8*)(wp + (size_t)t * 512);
            acc[t] = __builtin_amdgcn_mfma_f32_16x16x32_bf16(afrag, bfrag, acc[t], 0, 0, 0);
        }
    }
    ushort_t* __restrict__ hw = hl[wave];
    #pragma unroll
    for (int t = 0; t < 8; ++t) {
        const int col = t * 16 + m16;
        const float bv = bias[col];
        #pragma unroll
        for (int r = 0; r < 4; ++r) {
            hw[(quad * 4 + r) * 136 + col] = f2b(fmaxf(acc[t][r] + bv, 0.f));
        }
    }
    f32x4 acc2[3];
    f32x4 acc3[3];
    #pragma unroll
    for (int t = 0; t < 3; ++t) {
        acc2[t] = (f32x4){0.f, 0.f, 0.f, 0.f};
        acc3[t] = (f32x4){0.f, 0.f, 0.f, 0.f};
    }
    #pragma unroll
    for (int kc = 0; kc < 4; ++kc) {
        const bf16x8 afrag2 = *(const bf16x8*)(hw + m16 * 136 + kc * 32 + quad * 8);
        const ushort_t* __restrict__ wp2  = Wp2  + (size_t)kc * 1536 + (size_t)lane * 8;
        const ushort_t* __restrict__ wp2r = Wp2r + (size_t)kc * 1536 + (size_t)lane * 8;
        #pragma unroll
        for (int t = 0; t < 3; ++t) {
            const bf16x8 bfrag  = *(const bf16x8*)(wp2  + (size_t)t * 512);
            const bf16x8 bfragr = *(const bf16x8*)(wp2r + (size_t)t * 512);
            acc2[t] = __builtin_amdgcn_mfma_f32_16x16x32_bf16(afrag2, bfrag,  acc2[t], 0, 0, 0);
            acc3[t] = __builtin_amdgcn_mfma_f32_16x16x32_bf16(afrag2, bfragr, acc3[t], 0, 0, 0);
        }
    }
    #pragma unroll
    for (int t = 0; t < 3; ++t) {
        const int col = t * 16 + m16;
        if (col >= NCLS) continue;
        #pragma unroll
        for (int r = 0; r < 4; ++r) {
            const int row = row0 + quad * 4 + r;
            if (row < n) {
                Cbf[(size_t)row * CPAD + col] = f2b(acc2[t][r]);
                Dfl[(size_t)row * NCLS + col] = acc3[t][r];
            }
        }
    }
}

// Fused layer-2 gather + softmax. Phase A: 4 lanes per node (edge-split),
// unrolled x2 -> 10 line-aligned loads in flight, butterfly 40->20->10.
// Phase B: lg = fmaf(gather, id, b2) + Dfl (dense branch precomputed by gemm).
__global__ __launch_bounds__(256) void final_kernel(
    const float* __restrict__ Dfl, const ushort_t* __restrict__ Cbf,
    const int* __restrict__ row_ptr, const int* __restrict__ eidx,
    const float* __restrict__ b2,
    float* __restrict__ out, int n)
{
    __shared__ float lgs[64][41];
    const int tid  = threadIdx.x;
    const int q    = tid >> 6;
    const int lane = tid & 63;
    const int r    = lane & 3;
    const int na   = q * 16 + (lane >> 2);      // node-in-block 0..63
    const int nodeA = blockIdx.x * 64 + na;
    float lg[40];
    #pragma unroll
    for (int c = 0; c < 40; ++c) lg[c] = 0.f;
    if (nodeA < n) {
        int j  = row_ptr[nodeA] + r;
        int je = row_ptr[nodeA + 1];
        for (; j + 4 < je; j += 8) {
            int s0 = eidx[j];
            int s1 = eidx[j + 4];
            const uint4a* __restrict__ p0 = (const uint4a*)(Cbf + (size_t)s0 * CPAD);
            const uint4a* __restrict__ p1 = (const uint4a*)(Cbf + (size_t)s1 * CPAD);
            uint4a a0 = p0[0], a1 = p0[1], a2 = p0[2], a3 = p0[3], a4 = p0[4];
            uint4a c0v = p1[0], c1 = p1[1], c2 = p1[2], c3 = p1[3], c4 = p1[4];
            acc_row40(lg, a0, a1, a2, a3, a4);
            acc_row40(lg, c0v, c1, c2, c3, c4);
        }
        if (j < je) {
            const uint4a* __restrict__ p0 = (const uint4a*)(Cbf + (size_t)eidx[j] * CPAD);
            uint4a a0 = p0[0], a1 = p0[1], a2 = p0[2], a3 = p0[3], a4 = p0[4];
            acc_row40(lg, a0, a1, a2, a3, a4);
        }
    }
    // transposed butterfly over 4-lane groups (no runtime array indexing)
    const bool hi1 = (lane & 1) != 0;
    float h20[20];
    #pragma unroll
    for (int i = 0; i < 20; ++i) {
        float sendv = hi1 ? lg[i] : lg[20 + i];
        float recv  = __shfl_xor(sendv, 1, 64);
        h20[i] = (hi1 ? lg[20 + i] : lg[i]) + recv;
    }
    const bool hi2 = (lane & 2) != 0;
    float h10[10];
    #pragma unroll
    for (int i = 0; i < 10; ++i) {
        float sendv = hi2 ? h20[i] : h20[10 + i];
        float recv  = __shfl_xor(sendv, 2, 64);
        h10[i] = (hi2 ? h20[10 + i] : h20[i]) + recv;
    }
    const int cbase = (hi1 ? 20 : 0) + (hi2 ? 10 : 0);
    #pragma unroll
    for (int i = 0; i < 10; ++i) lgs[na][cbase + i] = h10[i];
    __syncthreads();
    // Phase B: wave q -> cols [10q,10q+10), lane = node-in-block
    const int c0 = __builtin_amdgcn_readfirstlane(q * 10);
    const int node = blockIdx.x * 64 + lane;
    if (node < n) {
        const float dg = (float)(row_ptr[node + 1] - row_ptr[node]);
        const float id = 1.0f / fmaxf(dg, 1.0f);
        const float* __restrict__ drow = Dfl + (size_t)node * NCLS + c0;
        #pragma unroll
        for (int c = 0; c < 10; ++c)
            lgs[lane][c0 + c] = fmaf(lgs[lane][c0 + c], id, b2[c0 + c]) + drow[c];
    }
    __syncthreads();
    if (q == 0 && node < n) {
        float v[NCLS];
        #pragma unroll
        for (int c = 0; c < NCLS; ++c) v[c] = lgs[lane][c];
        float m = v[0];
        #pragma unroll
        for (int c = 1; c < NCLS; ++c) m = fmaxf(m, v[c]);
        float s = 0.f;
        #pragma unroll
        for (int c = 0; c < NCLS; ++c) { v[c] = __expf(v[c] - m); s += v[c]; }
        const float inv = 1.0f / s;
        float* __restrict__ o = out + (size_t)node * NCLS;
        #pragma unroll
        for (int c = 0; c < NCLS; ++c) o[c] = v[c] * inv;
    }
}

extern "C" void kernel_launch(void* const* d_in, const int* in_sizes, int n_in,
                              void* d_out, int out_size, void* d_ws, size_t ws_size,
                              hipStream_t stream) {
    const float* x   = (const float*)d_in[0];
    const int*   ei  = (const int*)d_in[1];
    const float* W1l = (const float*)d_in[2];
    const float* W1r = (const float*)d_in[3];
    const float* b1  = (const float*)d_in[4];
    const float* W2l = (const float*)d_in[5];
    const float* W2r = (const float*)d_in[6];
    const float* b2  = (const float*)d_in[7];
    float* out = (float*)d_out;

    const int n = in_sizes[0] / DIM;   // 100000
    const int E = in_sizes[1] / 2;     // 1600000
    const int* src = ei;
    const int* dst = ei + E;

    // workspace layout (~105 MB):
    //   xbf (25.6M) | mxbf (25.6M) | Dfl (16M fp32) | Cbf (12.8M, CPAD=64)
    //   | xq (12.8M) | Wp (64K) | Wp2 (12K) | Wp2r (12K) | eidx[E]
    //   | pairs[E] (packed int, 6.4M) | row_ptr[n+1] | binCnt[256] | binCtr[256]
    ushort_t* xbf     = (ushort_t*)d_ws;
    ushort_t* mxbf    = xbf + (size_t)n * DIM;
    float*    Dfl     = (float*)(mxbf + (size_t)n * DIM);
    ushort_t* Cbf     = (ushort_t*)(Dfl + (size_t)n * NCLS);
    unsigned* xq      = (unsigned*)(Cbf + (size_t)n * CPAD);
    ushort_t* Wp      = (ushort_t*)(xq + (size_t)n * 32);
    ushort_t* Wp2     = Wp + 256 * DIM;
    ushort_t* Wp2r    = Wp2 + 4 * 1536;
    int*      eidx    = (int*)(Wp2r + 4 * 1536);
    unsigned* pairs   = (unsigned*)(eidx + E);
    int*      row_ptr = (int*)(pairs + E);
    int*      binCnt  = row_ptr + (n + 1);
    // binCtr = binCnt + NBIN (contiguous; zeroed together)

    // --- zero bin counters (graph-capturable memset node) ---
    hipMemsetAsync(binCnt, 0, 2 * NBIN * sizeof(int), stream);

    // --- fused prep (cast + weight packs + bincount) ---
    const int n4 = n * 32;                       // float4 items in x
    const int cb = (n4 + 255) / 256;             // cast blocks
    prep_kernel<<<cb + 176 + 256, 256, 0, stream>>>(x, xbf, xq, W1r, W1l, Wp,
                                                    W2l, Wp2, W2r, Wp2r,
                                                    dst, binCnt, E, n4, cb);

    // --- CSR build via binned counting sort ---
    binscatter_kernel<<<512, 256, 0, stream>>>(src, dst, binCnt, binCnt + NBIN, pairs, E);
    bincsr_kernel    <<<NBIN, 256, 0, stream>>>(pairs, binCnt, row_ptr, eidx, n, E);

    // --- layer 1 + layer-2 projections ---
    {
        long long t = (long long)n * 32;
        gather128_kernel<<<(int)((t + 255) / 256), 256, 0, stream>>>(xq, row_ptr, eidx, mxbf, n);
    }
    mfma_gemm_kernel<<<(n + 63) / 64, 256, 0, stream>>>(xbf, mxbf, Wp, Wp2, Wp2r,
                                                        b1, Cbf, Dfl, n);

    // --- layer 2: fused gather + softmax ---
    final_kernel<<<(n + 63) / 64, 256, 0, stream>>>(Dfl, Cbf, row_ptr, eidx, b2, out, n);
}